// Round 10
// baseline (717.351 us; speedup 1.0000x reference)
//
#include <hip/hip_runtime.h>
#include <math.h>

namespace {
constexpr int cB = 16, cN = 8192, cC = 64, cK = 128, cR = 4, cNL = 4;
constexpr float kTwoPi = 6.28318530717958647692f;

// workspace layout (float offsets)
constexpr size_t OFF_H     = 0;                                // 8,388,608
constexpr size_t OFF_PACKA = (size_t)cB * cC * cN;             // +524,288
constexpr size_t OFF_PACKB = OFF_PACKA + (size_t)cB * cN * 4;  // +524,288
constexpr size_t OFF_PACKC = OFF_PACKB + (size_t)cB * cN * 4;  // +262,144
constexpr size_t OFF_PC    = OFF_PACKC + (size_t)cB * cN * 2;  // 512 slots * 8192
constexpr size_t OFF_PS    = OFF_PC + (size_t)512 * 8192;
constexpr size_t OFF_XC    = OFF_PS + (size_t)512 * 8192;
constexpr size_t OFF_XS    = OFF_XC + (size_t)cB * cC * cK;
constexpr size_t OFF_FAH   = OFF_XS + (size_t)cB * cC * cK;    // 163,840 floats (327,680 halfs)
constexpr size_t OFF_FAL   = OFF_FAH + (size_t)cB * cC * 320 / 2;
constexpr size_t OFF_F0    = OFF_FAL + (size_t)cB * cC * 320 / 2;
// end = 18,678,784 floats = 74.7 MB

typedef _Float16 f16x8 __attribute__((ext_vector_type(8)));
typedef _Float16 f16x4 __attribute__((ext_vector_type(4)));
typedef float f32x4 __attribute__((ext_vector_type(4)));

__device__ __forceinline__ float gelu_f(float x) {
  return 0.5f * x * (1.0f + erff(x * 0.7071067811865475244f));
}

struct cpx { float x, y; };
__device__ __forceinline__ cpx cmul(cpx a, cpx b) {
  cpx r;
  r.x = fmaf(a.x, b.x, -(a.y * b.y));
  r.y = fmaf(a.x, b.y, a.y * b.x);
  return r;
}

__device__ __forceinline__ void split16(float v, _Float16& hi, _Float16& lo) {
  hi = (_Float16)v;
  lo = (_Float16)((v - (float)hi) * 1024.0f);
}
}  // namespace

// --- prep: fc0 into (B,C,N), per-point phase factors
__global__ void __launch_bounds__(256) k_prep(const float* __restrict__ x,
                                              const float* __restrict__ fc0_w,
                                              const float* __restrict__ fc0_b,
                                              float* __restrict__ ws) {
  int t = blockIdx.x * 256 + threadIdx.x;
  int b = t >> 13;
  int n = t & (cN - 1);
  const float* xp = x + (size_t)t * 7;
  float f0 = xp[0], f1 = xp[1], f2 = xp[2];
  float gx = xp[3], gy = xp[4], w = xp[5], m = xp[6];
  float ax = kTwoPi * gx, ay = kTwoPi * gy;
  float sx, cx, sy, cy, s8x, c8x, s4y, c4y;
  sincosf(ax, &sx, &cx);
  sincosf(ay, &sy, &cy);
  sincosf(8.0f * ax, &s8x, &c8x);
  sincosf(4.0f * ay, &s4y, &c4y);
  ((float4*)(ws + OFF_PACKA))[t] = make_float4(cx, sx, cy, sy);
  ((float4*)(ws + OFF_PACKB))[t] = make_float4(c8x, s8x, c4y, s4y);
  ((float2*)(ws + OFF_PACKC))[t] = make_float2(w * (float)cN * m, m);
  float* h = ws + OFF_H + (size_t)b * cC * cN + n;
#pragma unroll
  for (int c = 0; c < cC; c++) {
    float v = fc0_b[c] + f0 * fc0_w[c] + f1 * fc0_w[cC + c] + f2 * fc0_w[2 * cC + c];
    h[(size_t)c * cN] = v;
  }
}

// --- forward (MFMA split-fp16): per-block partial Xc/Xs, 512 blocks.
__global__ void __launch_bounds__(256, 2) k_forward(const float* __restrict__ hg,
                                                    const float* __restrict__ ws,
                                                    float* __restrict__ Pc,
                                                    float* __restrict__ Ps) {
  __shared__ __align__(16) _Float16 lAh[64 * 40];
  __shared__ __align__(16) _Float16 lAl[64 * 40];
  __shared__ __align__(16) _Float16 lWh[256 * 40];
  __shared__ __align__(16) _Float16 lWl[256 * 40];
  int b = blockIdx.y, nb = blockIdx.x;  // nb 0..31
  int n_base = nb * 256;
  int tid = threadIdx.x;
  int lane = tid & 63, w = tid >> 6;
  int l15 = lane & 15, quad = lane >> 4;
  int sc = tid & 63, skg = tid >> 6;   // H: channel, 8-pt group
  int mg = tid >> 3, pg = tid & 7;     // W: 4-mode group, 4-pt group
  int kx = mg >> 1, ky0 = (mg & 1) * 4;
  const float4* pA = (const float4*)(ws + OFF_PACKA) + (size_t)b * cN;
  const float4* pB = (const float4*)(ws + OFF_PACKB) + (size_t)b * cN;
  const float2* pC = (const float2*)(ws + OFF_PACKC) + (size_t)b * cN;
  const float* hb = hg + (size_t)b * cC * cN;
  f32x4 acc0[4][4], acc1[4][4];
  f32x4 zz = {0.0f, 0.0f, 0.0f, 0.0f};
#pragma unroll
  for (int i = 0; i < 4; i++)
#pragma unroll
    for (int j = 0; j < 4; j++) { acc0[i][j] = zz; acc1[i][j] = zz; }

  for (int s = 0; s < 8; s++) {
    int n0 = n_base + s * 32;
    {
      const float* hrow = hb + (size_t)sc * cN + n0 + skg * 8;
      float4 va = *(const float4*)hrow;
      float4 vb = *(const float4*)(hrow + 4);
      float vals[8] = {va.x, va.y, va.z, va.w, vb.x, vb.y, vb.z, vb.w};
      f16x8 hi8, lo8;
#pragma unroll
      for (int e = 0; e < 8; e++) {
        _Float16 hv, lv;
        split16(vals[e], hv, lv);
        hi8[e] = hv;
        lo8[e] = lv;
      }
      *(f16x8*)&lAh[sc * 40 + skg * 8] = hi8;
      *(f16x8*)&lAl[sc * 40 + skg * 8] = lo8;
    }
    {
      _Float16 chi[4][4], clo[4][4], shi[4][4], slo[4][4];  // [j][q]
#pragma unroll
      for (int q = 0; q < 4; q++) {
        int p = n0 + pg * 4 + q;
        float4 a4 = pA[p];
        float4 b4 = pB[p];
        float wsz = pC[p].x;
        cpx ex{a4.x, a4.y}, ey{a4.z, a4.w}, ex8{b4.x, b4.y}, ey4{b4.z, b4.w};
        cpx ex2 = cmul(ex, ex);
        cpx ex4v = cmul(ex2, ex2);
        cpx u{wsz, 0.0f};
        if (kx & 1) u = cmul(u, ex);
        if (kx & 2) u = cmul(u, ex2);
        if (kx & 4) u = cmul(u, ex4v);
        if (kx & 8) u = cmul(u, ex8);
        cpx v;
        if (ky0) v = ey4; else v = cpx{1.0f, 0.0f};
#pragma unroll
        for (int j = 0; j < 4; j++) {
          cpx m = cmul(u, v);
          split16(m.x, chi[j][q], clo[j][q]);
          split16(m.y, shi[j][q], slo[j][q]);
          v = cmul(v, ey);
        }
      }
      int mbase = kx * 8 + ky0;
#pragma unroll
      for (int j = 0; j < 4; j++) {
        int mc = mbase + j, ms = 128 + mbase + j;
        f16x4 t0 = {chi[j][0], chi[j][1], chi[j][2], chi[j][3]};
        f16x4 t1 = {clo[j][0], clo[j][1], clo[j][2], clo[j][3]};
        f16x4 t2 = {shi[j][0], shi[j][1], shi[j][2], shi[j][3]};
        f16x4 t3 = {slo[j][0], slo[j][1], slo[j][2], slo[j][3]};
        *(f16x4*)&lWh[mc * 40 + pg * 4] = t0;
        *(f16x4*)&lWl[mc * 40 + pg * 4] = t1;
        *(f16x4*)&lWh[ms * 40 + pg * 4] = t2;
        *(f16x4*)&lWl[ms * 40 + pg * 4] = t3;
      }
    }
    __syncthreads();
    f16x8 Ahf[4], Alf[4];
#pragma unroll
    for (int mt = 0; mt < 4; mt++) {
      Ahf[mt] = *(const f16x8*)&lAh[(mt * 16 + l15) * 40 + quad * 8];
      Alf[mt] = *(const f16x8*)&lAl[(mt * 16 + l15) * 40 + quad * 8];
    }
#pragma unroll
    for (int nt = 0; nt < 4; nt++) {
      int row = w * 64 + nt * 16 + l15;
      f16x8 Bh = *(const f16x8*)&lWh[row * 40 + quad * 8];
      f16x8 Bl = *(const f16x8*)&lWl[row * 40 + quad * 8];
#pragma unroll
      for (int mt = 0; mt < 4; mt++) {
        acc0[mt][nt] = __builtin_amdgcn_mfma_f32_16x16x32_f16(Ahf[mt], Bh, acc0[mt][nt], 0, 0, 0);
        acc1[mt][nt] = __builtin_amdgcn_mfma_f32_16x16x32_f16(Ahf[mt], Bl, acc1[mt][nt], 0, 0, 0);
        acc1[mt][nt] = __builtin_amdgcn_mfma_f32_16x16x32_f16(Alf[mt], Bh, acc1[mt][nt], 0, 0, 0);
      }
    }
    __syncthreads();
  }
  float* pcb = Pc + (size_t)(b * 32 + nb) * 8192;
  float* psb = Ps + (size_t)(b * 32 + nb) * 8192;
  const float inv1024 = 1.0f / 1024.0f;
#pragma unroll
  for (int mt = 0; mt < 4; mt++)
#pragma unroll
    for (int nt = 0; nt < 4; nt++) {
      int nn = w * 64 + nt * 16 + l15;
      float* dst = (nn < 128) ? pcb : psb;
      int col = nn & 127;
#pragma unroll
      for (int r = 0; r < 4; r++) {
        int c = mt * 16 + quad * 4 + r;
        dst[c * 128 + col] = acc0[mt][nt][r] + acc1[mt][nt][r] * inv1024;
      }
    }
}

// --- reduce 32 partials -> Xc/Xs
__global__ void __launch_bounds__(256) k_reduce(const float* __restrict__ Pc,
                                                const float* __restrict__ Ps,
                                                float* __restrict__ Xc,
                                                float* __restrict__ Xs) {
  int idx = blockIdx.x * 256 + threadIdx.x;  // 0..131071
  int b = idx >> 13;
  int rest = idx & 8191;
  float sc = 0.0f, ss = 0.0f;
#pragma unroll
  for (int nb = 0; nb < 32; nb++) {
    sc += Pc[(size_t)(b * 32 + nb) * 8192 + rest];
    ss += Ps[(size_t)(b * 32 + nb) * 8192 + rest];
  }
  Xc[idx] = sc;
  Xs[idx] = ss;
}

// --- low-rank mixing; one wave per (b,k); writes split-fp16 A-matrix for k_inverse:
//     A rows: super-chunk sc=k>>5: row 64*sc + (k&31) = scale*fc (cos),
//             +32 = -scale*fs (sin); rows 256+i = wconv[i][c] (written by blocks k<64).
__global__ void __launch_bounds__(64) k_lowrank(const float* __restrict__ Xc,
                                                const float* __restrict__ Xs,
                                                const float* __restrict__ wc1,
                                                const float* __restrict__ wc2,
                                                const float* __restrict__ ws1,
                                                const float* __restrict__ ws2,
                                                const float* __restrict__ w01,
                                                const float* __restrict__ w02,
                                                const float* __restrict__ wconv,
                                                float* __restrict__ ws, int layer) {
  int b = blockIdx.x;
  int k = blockIdx.y;
  int tid = threadIdx.x;
  const float* xcb = Xc + (size_t)b * cC * cK;
  const float* xsb = Xs + (size_t)b * cC * cK;
  float xcv = xcb[(size_t)tid * cK + k];
  float xsv = -xsb[(size_t)tid * cK + k];
  const float* c1 = wc1 + (size_t)layer * cC * cR * cK + (size_t)tid * cR * cK + k;
  const float* s1 = ws1 + (size_t)layer * cC * cR * cK + (size_t)tid * cR * cK + k;
  float A1[cR], A2[cR], B1[cR], B2[cR];
#pragma unroll
  for (int r = 0; r < cR; r++) {
    float w1c = c1[(size_t)r * cK];
    float w1sv = s1[(size_t)r * cK];
    A1[r] = xcv * w1c;
    A2[r] = xcv * w1sv;
    B1[r] = xsv * w1c;
    B2[r] = xsv * w1sv;
  }
#pragma unroll
  for (int r = 0; r < cR; r++) {
#pragma unroll
    for (int off = 32; off > 0; off >>= 1) {
      A1[r] += __shfl_xor(A1[r], off);
      A2[r] += __shfl_xor(A2[r], off);
      B1[r] += __shfl_xor(B1[r], off);
      B2[r] += __shfl_xor(B2[r], off);
    }
  }
  const float scale = 2.0f / (float)cN;
  const float* c2 = wc2 + (size_t)layer * cR * cC * cK;
  const float* s2 = ws2 + (size_t)layer * cR * cC * cK;
  int o = tid;
  float fc = 0.0f, fs = 0.0f;
#pragma unroll
  for (int r = 0; r < cR; r++) {
    float w2c = c2[((size_t)r * cC + o) * cK + k];
    float w2s = s2[((size_t)r * cC + o) * cK + k];
    fc += A1[r] * w2c - B2[r] * w2s;
    fs += B1[r] * w2c + A2[r] * w2s;
  }
  _Float16* FAh = (_Float16*)(ws + OFF_FAH);
  _Float16* FAl = (_Float16*)(ws + OFF_FAL);
  size_t abase = ((size_t)b * cC + o) * 320;
  int rowc = ((k >> 5) << 6) + (k & 31);
  float vc = scale * fc;
  float vs = -scale * fs;
  _Float16 hi, lo;
  split16(vc, hi, lo);
  FAh[abase + rowc] = hi;
  FAl[abase + rowc] = lo;
  split16(vs, hi, lo);
  FAh[abase + rowc + 32] = hi;
  FAl[abase + rowc + 32] = lo;
  if (k < 64) {
    float wv = wconv[(size_t)layer * 4096 + (size_t)k * cC + o];
    split16(wv, hi, lo);
    FAh[abase + 256 + k] = hi;
    FAl[abase + 256 + k] = lo;
  }
  if (k == 0) {
    float t0[cR];
#pragma unroll
    for (int r = 0; r < cR; r++)
      t0[r] = xcv * w01[((size_t)layer * cC + tid) * cR + r];
#pragma unroll
    for (int r = 0; r < cR; r++) {
#pragma unroll
      for (int off = 32; off > 0; off >>= 1) t0[r] += __shfl_xor(t0[r], off);
    }
    float f = 0.0f;
#pragma unroll
    for (int r = 0; r < cR; r++) f += t0[r] * w02[((size_t)layer * cR + r) * cC + o];
    (ws + OFF_F0)[b * cC + o] = f / (float)cN;
  }
}

// --- inverse v5 (MFMA split-fp16): one K=320 GEMM per 64-pt block.
//     D[c,n] = sum_k A[k,c]*B[k,n]; A from global (L1-broadcast across waves),
//     B = bases*mask (LDS, gen per super-chunk) + h (register frags, pre-barrier).
__global__ void __launch_bounds__(256, 2) k_inverse(float* __restrict__ h,
                                                    const float* __restrict__ ws,
                                                    const float* __restrict__ bconv,
                                                    int layer, int do_gelu) {
  __shared__ __align__(16) _Float16 Bsh[64 * 72];
  __shared__ __align__(16) _Float16 Bsl[64 * 72];
  int b = blockIdx.y;
  int n_blk = blockIdx.x * 64;
  int tid = threadIdx.x;
  int lane = tid & 63, w = tid >> 6;
  int l15 = lane & 15, quad = lane >> 4;
  int p = tid >> 2, sub = tid & 3;
  const float4* pA = (const float4*)(ws + OFF_PACKA) + (size_t)b * cN;
  const float4* pB = (const float4*)(ws + OFF_PACKB) + (size_t)b * cN;
  const float2* pC = (const float2*)(ws + OFF_PACKC) + (size_t)b * cN;
  // anchors for basis point p
  float4 a4 = pA[n_blk + p];
  float4 b4 = pB[n_blk + p];
  float mval_p = pC[n_blk + p].y;
  cpx ex{a4.x, a4.y}, ey{a4.z, a4.w}, ex8{b4.x, b4.y}, ey4{b4.z, b4.w};
  cpx ex2 = cmul(ex, ex);
  cpx ex3 = cmul(ex2, ex);
  cpx ex4v = cmul(ex2, ex2);
  cpx ex12 = cmul(ex8, ex4v);
  cpx eyp[8];
  eyp[0] = {1.0f, 0.0f};
  eyp[1] = ey;
  eyp[2] = cmul(ey, ey);
  eyp[3] = cmul(eyp[2], ey);
  eyp[4] = ey4;
  eyp[5] = cmul(ey4, ey);
  eyp[6] = cmul(ey4, eyp[2]);
  eyp[7] = cmul(ey4, eyp[3]);
  // this lane's output column + mask
  int ncol = n_blk + w * 16 + l15;
  float mcol = pC[ncol].y;
  // conv B-frags from fp32 h, read BEFORE first barrier (in-place safe:
  // stores happen after the last barrier)
  float* hb = h + (size_t)b * cC * cN;
  f16x8 cBh[2], cBl[2];
#pragma unroll
  for (int t = 0; t < 2; t++) {
#pragma unroll
    for (int j = 0; j < 8; j++) {
      int i = t * 32 + quad * 8 + j;
      float v = hb[(size_t)i * cN + ncol];
      _Float16 hi, lo;
      split16(v, hi, lo);
      cBh[t][j] = hi;
      cBl[t][j] = lo;
    }
  }
  const _Float16* FAh = (const _Float16*)(ws + OFF_FAH) + (size_t)b * cC * 320;
  const _Float16* FAl = (const _Float16*)(ws + OFF_FAL) + (size_t)b * cC * 320;
  f32x4 acc0[4], acc1[4];
  f32x4 zz = {0.0f, 0.0f, 0.0f, 0.0f};
#pragma unroll
  for (int i = 0; i < 4; i++) { acc0[i] = zz; acc1[i] = zz; }
  for (int sc = 0; sc < 4; sc++) {
    __syncthreads();  // previous Bst consumed
    // basis gen for kx = 4sc + sub, all ky; mask folded
    cpx base;
    if (sc == 0) base = cpx{1.0f, 0.0f};
    else if (sc == 1) base = ex4v;
    else if (sc == 2) base = ex8;
    else base = ex12;
    cpx u;
    if (sub == 0) u = base;
    else if (sub == 1) u = cmul(base, ex);
    else if (sub == 2) u = cmul(base, ex2);
    else u = cmul(base, ex3);
    u.x *= mval_p;
    u.y *= mval_p;
    f16x8 ch, cl, sh, sl;
#pragma unroll
    for (int ky = 0; ky < 8; ky++) {
      cpx m = cmul(u, eyp[ky]);
      _Float16 hi, lo;
      split16(m.x, hi, lo);
      ch[ky] = hi; cl[ky] = lo;
      split16(m.y, hi, lo);
      sh[ky] = hi; sl[ky] = lo;
    }
    *(f16x8*)&Bsh[p * 72 + sub * 8] = ch;
    *(f16x8*)&Bsl[p * 72 + sub * 8] = cl;
    *(f16x8*)&Bsh[p * 72 + 32 + sub * 8] = sh;
    *(f16x8*)&Bsl[p * 72 + 32 + sub * 8] = sl;
    __syncthreads();
#pragma unroll
    for (int t = 0; t < 2; t++) {
      int krow = sc * 64 + t * 32;
      f16x8 Af_h[4], Af_l[4];
#pragma unroll
      for (int mt = 0; mt < 4; mt++) {
        size_t aoff = (size_t)(mt * 16 + l15) * 320 + krow + quad * 8;
        Af_h[mt] = *(const f16x8*)&FAh[aoff];
        Af_l[mt] = *(const f16x8*)&FAl[aoff];
      }
      f16x8 Bf_h = *(const f16x8*)&Bsh[(w * 16 + l15) * 72 + t * 32 + quad * 8];
      f16x8 Bf_l = *(const f16x8*)&Bsl[(w * 16 + l15) * 72 + t * 32 + quad * 8];
#pragma unroll
      for (int mt = 0; mt < 4; mt++) {
        acc0[mt] = __builtin_amdgcn_mfma_f32_16x16x32_f16(Af_h[mt], Bf_h, acc0[mt], 0, 0, 0);
        acc1[mt] = __builtin_amdgcn_mfma_f32_16x16x32_f16(Af_h[mt], Bf_l, acc1[mt], 0, 0, 0);
        acc1[mt] = __builtin_amdgcn_mfma_f32_16x16x32_f16(Af_l[mt], Bf_h, acc1[mt], 0, 0, 0);
      }
    }
  }
  // conv chunks (K rows 256..319), B-frags from registers
#pragma unroll
  for (int t = 0; t < 2; t++) {
    int krow = 256 + t * 32;
    f16x8 Af_h[4], Af_l[4];
#pragma unroll
    for (int mt = 0; mt < 4; mt++) {
      size_t aoff = (size_t)(mt * 16 + l15) * 320 + krow + quad * 8;
      Af_h[mt] = *(const f16x8*)&FAh[aoff];
      Af_l[mt] = *(const f16x8*)&FAl[aoff];
    }
#pragma unroll
    for (int mt = 0; mt < 4; mt++) {
      acc0[mt] = __builtin_amdgcn_mfma_f32_16x16x32_f16(Af_h[mt], cBh[t], acc0[mt], 0, 0, 0);
      acc1[mt] = __builtin_amdgcn_mfma_f32_16x16x32_f16(Af_h[mt], cBl[t], acc1[mt], 0, 0, 0);
      acc1[mt] = __builtin_amdgcn_mfma_f32_16x16x32_f16(Af_l[mt], cBh[t], acc1[mt], 0, 0, 0);
    }
  }
  // epilogue: + F0*mask + bconv, gelu, store (C/D: col=l15, row=quad*4+r)
  const float* F0B = ws + OFF_F0 + (size_t)b * cC;
  const float inv1024 = 1.0f / 1024.0f;
#pragma unroll
  for (int mt = 0; mt < 4; mt++) {
#pragma unroll
    for (int r = 0; r < 4; r++) {
      int row = mt * 16 + quad * 4 + r;
      float v = acc0[mt][r] + acc1[mt][r] * inv1024 + F0B[row] * mcol +
                bconv[layer * cC + row];
      if (do_gelu) v = gelu_f(v);
      hb[(size_t)row * cN + ncol] = v;
    }
  }
}

// --- final MLP: gelu(h^T @ fc1 + b1) @ fc2 + b2
__global__ void __launch_bounds__(256) k_final(const float* __restrict__ h,
                                               const float* __restrict__ fc1_w,
                                               const float* __restrict__ fc1_b,
                                               const float* __restrict__ fc2_w,
                                               const float* __restrict__ fc2_b,
                                               float* __restrict__ out) {
  int b = blockIdx.y;
  int n0 = blockIdx.x * 64;
  int tid = threadIdx.x;
  int tn = tid & 63;
  int tg = tid >> 6;
  __shared__ __align__(16) float w1s[cC * 128];
  __shared__ __align__(16) float hT[cC * 64];
  __shared__ float red[4 * 64];
  const float* hb = h + (size_t)b * cC * cN;
#pragma unroll
  for (int i = 0; i < 16; i++) {
    int e = tid + i * 256;
    int c = e >> 6, nnx = e & 63;
    hT[c * 64 + nnx] = hb[(size_t)c * cN + n0 + nnx];
  }
#pragma unroll
  for (int i = 0; i < 32; i++) {
    int e = tid + i * 256;
    w1s[e] = fc1_w[e];
  }
  __syncthreads();
  int j0 = tg * 32;
  float acc[32] = {};
  for (int c = 0; c < cC; c++) {
    float hv = hT[c * 64 + tn];
#pragma unroll
    for (int jj = 0; jj < 32; jj += 4) {
      float4 w4 = *(const float4*)&w1s[c * 128 + j0 + jj];
      acc[jj] += hv * w4.x;
      acc[jj + 1] += hv * w4.y;
      acc[jj + 2] += hv * w4.z;
      acc[jj + 3] += hv * w4.w;
    }
  }
  float s = 0.0f;
#pragma unroll
  for (int jj = 0; jj < 32; jj++) {
    int j = j0 + jj;
    float v = gelu_f(acc[jj] + fc1_b[j]);
    s += v * fc2_w[j];
  }
  red[tg * 64 + tn] = s;
  __syncthreads();
  if (tg == 0) {
    float r = red[tn] + red[64 + tn] + red[128 + tn] + red[192 + tn] + fc2_b[0];
    out[(size_t)b * cN + n0 + tn] = r;
  }
}

extern "C" void kernel_launch(void* const* d_in, const int* in_sizes, int n_in,
                              void* d_out, int out_size, void* d_ws, size_t ws_size,
                              hipStream_t stream) {
  const float* x = (const float*)d_in[0];
  const float* fc0_w = (const float*)d_in[1];
  const float* fc0_b = (const float*)d_in[2];
  const float* wc1 = (const float*)d_in[3];
  const float* wc2 = (const float*)d_in[4];
  const float* ws1 = (const float*)d_in[5];
  const float* ws2 = (const float*)d_in[6];
  const float* w01 = (const float*)d_in[7];
  const float* w02 = (const float*)d_in[8];
  const float* wconv = (const float*)d_in[9];
  const float* bconv = (const float*)d_in[10];
  const float* fc1_w = (const float*)d_in[11];
  const float* fc1_b = (const float*)d_in[12];
  const float* fc2_w = (const float*)d_in[13];
  const float* fc2_b = (const float*)d_in[14];
  float* ws = (float*)d_ws;
  float* out = (float*)d_out;
  float* h = ws + OFF_H;

  hipLaunchKernelGGL(k_prep, dim3(cB * cN / 256), dim3(256), 0, stream, x, fc0_w, fc0_b, ws);
  for (int l = 0; l < cNL; l++) {
    hipLaunchKernelGGL(k_forward, dim3(32, cB), dim3(256), 0, stream, h, ws,
                       ws + OFF_PC, ws + OFF_PS);
    hipLaunchKernelGGL(k_reduce, dim3(512), dim3(256), 0, stream,
                       ws + OFF_PC, ws + OFF_PS, ws + OFF_XC, ws + OFF_XS);
    hipLaunchKernelGGL(k_lowrank, dim3(cB, cK), dim3(64), 0, stream, ws + OFF_XC,
                       ws + OFF_XS, wc1, wc2, ws1, ws2, w01, w02, wconv, ws, l);
    hipLaunchKernelGGL(k_inverse, dim3(cN / 64, cB), dim3(256), 0, stream, h, ws,
                       bconv, l, (l != cNL - 1) ? 1 : 0);
  }
  hipLaunchKernelGGL(k_final, dim3(cN / 64, cB), dim3(256), 0, stream, h, fc1_w,
                     fc1_b, fc2_w, fc2_b, out);
}

// Round 11
// 486.615 us; speedup vs baseline: 1.4742x; 1.4742x over previous
//
#include <hip/hip_runtime.h>
#include <math.h>

namespace {
constexpr int cB = 16, cN = 8192, cC = 64, cK = 128, cR = 4, cNL = 4;
constexpr float kTwoPi = 6.28318530717958647692f;

// workspace layout (float offsets)
constexpr size_t OFF_H     = 0;                                // 8,388,608
constexpr size_t OFF_PACKA = (size_t)cB * cC * cN;             // +524,288
constexpr size_t OFF_PACKB = OFF_PACKA + (size_t)cB * cN * 4;  // +524,288
constexpr size_t OFF_PACKC = OFF_PACKB + (size_t)cB * cN * 4;  // +262,144
constexpr size_t OFF_PC    = OFF_PACKC + (size_t)cB * cN * 2;  // 512 slots * 8192
constexpr size_t OFF_PS    = OFF_PC + (size_t)512 * 8192;
constexpr size_t OFF_XC    = OFF_PS + (size_t)512 * 8192;
constexpr size_t OFF_XS    = OFF_XC + (size_t)cB * cC * cK;
constexpr size_t OFF_FAH   = OFF_XS + (size_t)cB * cC * cK;    // 163,840 floats (327,680 halfs)
constexpr size_t OFF_FAL   = OFF_FAH + (size_t)cB * cC * 320 / 2;
constexpr size_t OFF_F0    = OFF_FAL + (size_t)cB * cC * 320 / 2;
// end = 18,678,784 floats = 74.7 MB

typedef _Float16 f16x8 __attribute__((ext_vector_type(8)));
typedef _Float16 f16x4 __attribute__((ext_vector_type(4)));
typedef float f32x4 __attribute__((ext_vector_type(4)));

__device__ __forceinline__ float gelu_f(float x) {
  return 0.5f * x * (1.0f + erff(x * 0.7071067811865475244f));
}

struct cpx { float x, y; };
__device__ __forceinline__ cpx cmul(cpx a, cpx b) {
  cpx r;
  r.x = fmaf(a.x, b.x, -(a.y * b.y));
  r.y = fmaf(a.x, b.y, a.y * b.x);
  return r;
}

__device__ __forceinline__ void split16(float v, _Float16& hi, _Float16& lo) {
  hi = (_Float16)v;
  lo = (_Float16)((v - (float)hi) * 1024.0f);
}
}  // namespace

// --- prep: fc0 into (B,C,N), per-point phase factors
__global__ void __launch_bounds__(256) k_prep(const float* __restrict__ x,
                                              const float* __restrict__ fc0_w,
                                              const float* __restrict__ fc0_b,
                                              float* __restrict__ ws) {
  int t = blockIdx.x * 256 + threadIdx.x;
  int b = t >> 13;
  int n = t & (cN - 1);
  const float* xp = x + (size_t)t * 7;
  float f0 = xp[0], f1 = xp[1], f2 = xp[2];
  float gx = xp[3], gy = xp[4], w = xp[5], m = xp[6];
  float ax = kTwoPi * gx, ay = kTwoPi * gy;
  float sx, cx, sy, cy, s8x, c8x, s4y, c4y;
  sincosf(ax, &sx, &cx);
  sincosf(ay, &sy, &cy);
  sincosf(8.0f * ax, &s8x, &c8x);
  sincosf(4.0f * ay, &s4y, &c4y);
  ((float4*)(ws + OFF_PACKA))[t] = make_float4(cx, sx, cy, sy);
  ((float4*)(ws + OFF_PACKB))[t] = make_float4(c8x, s8x, c4y, s4y);
  ((float2*)(ws + OFF_PACKC))[t] = make_float2(w * (float)cN * m, m);
  float* h = ws + OFF_H + (size_t)b * cC * cN + n;
#pragma unroll
  for (int c = 0; c < cC; c++) {
    float v = fc0_b[c] + f0 * fc0_w[c] + f1 * fc0_w[cC + c] + f2 * fc0_w[2 * cC + c];
    h[(size_t)c * cN] = v;
  }
}

// --- forward (MFMA split-fp16): per-block partial Xc/Xs, 512 blocks.
__global__ void __launch_bounds__(256, 2) k_forward(const float* __restrict__ hg,
                                                    const float* __restrict__ ws,
                                                    float* __restrict__ Pc,
                                                    float* __restrict__ Ps) {
  __shared__ __align__(16) _Float16 lAh[64 * 40];
  __shared__ __align__(16) _Float16 lAl[64 * 40];
  __shared__ __align__(16) _Float16 lWh[256 * 40];
  __shared__ __align__(16) _Float16 lWl[256 * 40];
  int b = blockIdx.y, nb = blockIdx.x;  // nb 0..31
  int n_base = nb * 256;
  int tid = threadIdx.x;
  int lane = tid & 63, w = tid >> 6;
  int l15 = lane & 15, quad = lane >> 4;
  int sc = tid & 63, skg = tid >> 6;   // H: channel, 8-pt group
  int mg = tid >> 3, pg = tid & 7;     // W: 4-mode group, 4-pt group
  int kx = mg >> 1, ky0 = (mg & 1) * 4;
  const float4* pA = (const float4*)(ws + OFF_PACKA) + (size_t)b * cN;
  const float4* pB = (const float4*)(ws + OFF_PACKB) + (size_t)b * cN;
  const float2* pC = (const float2*)(ws + OFF_PACKC) + (size_t)b * cN;
  const float* hb = hg + (size_t)b * cC * cN;
  f32x4 acc0[4][4], acc1[4][4];
  f32x4 zz = {0.0f, 0.0f, 0.0f, 0.0f};
#pragma unroll
  for (int i = 0; i < 4; i++)
#pragma unroll
    for (int j = 0; j < 4; j++) { acc0[i][j] = zz; acc1[i][j] = zz; }

  for (int s = 0; s < 8; s++) {
    int n0 = n_base + s * 32;
    {
      const float* hrow = hb + (size_t)sc * cN + n0 + skg * 8;
      float4 va = *(const float4*)hrow;
      float4 vb = *(const float4*)(hrow + 4);
      float vals[8] = {va.x, va.y, va.z, va.w, vb.x, vb.y, vb.z, vb.w};
      f16x8 hi8, lo8;
#pragma unroll
      for (int e = 0; e < 8; e++) {
        _Float16 hv, lv;
        split16(vals[e], hv, lv);
        hi8[e] = hv;
        lo8[e] = lv;
      }
      *(f16x8*)&lAh[sc * 40 + skg * 8] = hi8;
      *(f16x8*)&lAl[sc * 40 + skg * 8] = lo8;
    }
    {
      _Float16 chi[4][4], clo[4][4], shi[4][4], slo[4][4];  // [j][q]
#pragma unroll
      for (int q = 0; q < 4; q++) {
        int p = n0 + pg * 4 + q;
        float4 a4 = pA[p];
        float4 b4 = pB[p];
        float wsz = pC[p].x;
        cpx ex{a4.x, a4.y}, ey{a4.z, a4.w}, ex8{b4.x, b4.y}, ey4{b4.z, b4.w};
        cpx ex2 = cmul(ex, ex);
        cpx ex4v = cmul(ex2, ex2);
        cpx u{wsz, 0.0f};
        if (kx & 1) u = cmul(u, ex);
        if (kx & 2) u = cmul(u, ex2);
        if (kx & 4) u = cmul(u, ex4v);
        if (kx & 8) u = cmul(u, ex8);
        cpx v;
        if (ky0) v = ey4; else v = cpx{1.0f, 0.0f};
#pragma unroll
        for (int j = 0; j < 4; j++) {
          cpx m = cmul(u, v);
          split16(m.x, chi[j][q], clo[j][q]);
          split16(m.y, shi[j][q], slo[j][q]);
          v = cmul(v, ey);
        }
      }
      int mbase = kx * 8 + ky0;
#pragma unroll
      for (int j = 0; j < 4; j++) {
        int mc = mbase + j, ms = 128 + mbase + j;
        f16x4 t0 = {chi[j][0], chi[j][1], chi[j][2], chi[j][3]};
        f16x4 t1 = {clo[j][0], clo[j][1], clo[j][2], clo[j][3]};
        f16x4 t2 = {shi[j][0], shi[j][1], shi[j][2], shi[j][3]};
        f16x4 t3 = {slo[j][0], slo[j][1], slo[j][2], slo[j][3]};
        *(f16x4*)&lWh[mc * 40 + pg * 4] = t0;
        *(f16x4*)&lWl[mc * 40 + pg * 4] = t1;
        *(f16x4*)&lWh[ms * 40 + pg * 4] = t2;
        *(f16x4*)&lWl[ms * 40 + pg * 4] = t3;
      }
    }
    __syncthreads();
    f16x8 Ahf[4], Alf[4];
#pragma unroll
    for (int mt = 0; mt < 4; mt++) {
      Ahf[mt] = *(const f16x8*)&lAh[(mt * 16 + l15) * 40 + quad * 8];
      Alf[mt] = *(const f16x8*)&lAl[(mt * 16 + l15) * 40 + quad * 8];
    }
#pragma unroll
    for (int nt = 0; nt < 4; nt++) {
      int row = w * 64 + nt * 16 + l15;
      f16x8 Bh = *(const f16x8*)&lWh[row * 40 + quad * 8];
      f16x8 Bl = *(const f16x8*)&lWl[row * 40 + quad * 8];
#pragma unroll
      for (int mt = 0; mt < 4; mt++) {
        acc0[mt][nt] = __builtin_amdgcn_mfma_f32_16x16x32_f16(Ahf[mt], Bh, acc0[mt][nt], 0, 0, 0);
        acc1[mt][nt] = __builtin_amdgcn_mfma_f32_16x16x32_f16(Ahf[mt], Bl, acc1[mt][nt], 0, 0, 0);
        acc1[mt][nt] = __builtin_amdgcn_mfma_f32_16x16x32_f16(Alf[mt], Bh, acc1[mt][nt], 0, 0, 0);
      }
    }
    __syncthreads();
  }
  float* pcb = Pc + (size_t)(b * 32 + nb) * 8192;
  float* psb = Ps + (size_t)(b * 32 + nb) * 8192;
  const float inv1024 = 1.0f / 1024.0f;
#pragma unroll
  for (int mt = 0; mt < 4; mt++)
#pragma unroll
    for (int nt = 0; nt < 4; nt++) {
      int nn = w * 64 + nt * 16 + l15;
      float* dst = (nn < 128) ? pcb : psb;
      int col = nn & 127;
#pragma unroll
      for (int r = 0; r < 4; r++) {
        int c = mt * 16 + quad * 4 + r;
        dst[c * 128 + col] = acc0[mt][nt][r] + acc1[mt][nt][r] * inv1024;
      }
    }
}

// --- reduce 32 partials -> Xc/Xs
__global__ void __launch_bounds__(256) k_reduce(const float* __restrict__ Pc,
                                                const float* __restrict__ Ps,
                                                float* __restrict__ Xc,
                                                float* __restrict__ Xs) {
  int idx = blockIdx.x * 256 + threadIdx.x;  // 0..131071
  int b = idx >> 13;
  int rest = idx & 8191;
  float sc = 0.0f, ss = 0.0f;
#pragma unroll
  for (int nb = 0; nb < 32; nb++) {
    sc += Pc[(size_t)(b * 32 + nb) * 8192 + rest];
    ss += Ps[(size_t)(b * 32 + nb) * 8192 + rest];
  }
  Xc[idx] = sc;
  Xs[idx] = ss;
}

// --- low-rank mixing; one wave per (b,k); writes split-fp16 A-matrix for k_inverse
__global__ void __launch_bounds__(64) k_lowrank(const float* __restrict__ Xc,
                                                const float* __restrict__ Xs,
                                                const float* __restrict__ wc1,
                                                const float* __restrict__ wc2,
                                                const float* __restrict__ ws1,
                                                const float* __restrict__ ws2,
                                                const float* __restrict__ w01,
                                                const float* __restrict__ w02,
                                                const float* __restrict__ wconv,
                                                float* __restrict__ ws, int layer) {
  int b = blockIdx.x;
  int k = blockIdx.y;
  int tid = threadIdx.x;
  const float* xcb = Xc + (size_t)b * cC * cK;
  const float* xsb = Xs + (size_t)b * cC * cK;
  float xcv = xcb[(size_t)tid * cK + k];
  float xsv = -xsb[(size_t)tid * cK + k];
  const float* c1 = wc1 + (size_t)layer * cC * cR * cK + (size_t)tid * cR * cK + k;
  const float* s1 = ws1 + (size_t)layer * cC * cR * cK + (size_t)tid * cR * cK + k;
  float A1[cR], A2[cR], B1[cR], B2[cR];
#pragma unroll
  for (int r = 0; r < cR; r++) {
    float w1c = c1[(size_t)r * cK];
    float w1sv = s1[(size_t)r * cK];
    A1[r] = xcv * w1c;
    A2[r] = xcv * w1sv;
    B1[r] = xsv * w1c;
    B2[r] = xsv * w1sv;
  }
#pragma unroll
  for (int r = 0; r < cR; r++) {
#pragma unroll
    for (int off = 32; off > 0; off >>= 1) {
      A1[r] += __shfl_xor(A1[r], off);
      A2[r] += __shfl_xor(A2[r], off);
      B1[r] += __shfl_xor(B1[r], off);
      B2[r] += __shfl_xor(B2[r], off);
    }
  }
  const float scale = 2.0f / (float)cN;
  const float* c2 = wc2 + (size_t)layer * cR * cC * cK;
  const float* s2 = ws2 + (size_t)layer * cR * cC * cK;
  int o = tid;
  float fc = 0.0f, fs = 0.0f;
#pragma unroll
  for (int r = 0; r < cR; r++) {
    float w2c = c2[((size_t)r * cC + o) * cK + k];
    float w2s = s2[((size_t)r * cC + o) * cK + k];
    fc += A1[r] * w2c - B2[r] * w2s;
    fs += B1[r] * w2c + A2[r] * w2s;
  }
  _Float16* FAh = (_Float16*)(ws + OFF_FAH);
  _Float16* FAl = (_Float16*)(ws + OFF_FAL);
  size_t abase = ((size_t)b * cC + o) * 320;
  int rowc = ((k >> 5) << 6) + (k & 31);
  float vc = scale * fc;
  float vs = -scale * fs;
  _Float16 hi, lo;
  split16(vc, hi, lo);
  FAh[abase + rowc] = hi;
  FAl[abase + rowc] = lo;
  split16(vs, hi, lo);
  FAh[abase + rowc + 32] = hi;
  FAl[abase + rowc + 32] = lo;
  if (k < 64) {
    float wv = wconv[(size_t)layer * 4096 + (size_t)k * cC + o];
    split16(wv, hi, lo);
    FAh[abase + 256 + k] = hi;
    FAl[abase + 256 + k] = lo;
  }
  if (k == 0) {
    float t0[cR];
#pragma unroll
    for (int r = 0; r < cR; r++)
      t0[r] = xcv * w01[((size_t)layer * cC + tid) * cR + r];
#pragma unroll
    for (int r = 0; r < cR; r++) {
#pragma unroll
      for (int off = 32; off > 0; off >>= 1) t0[r] += __shfl_xor(t0[r], off);
    }
    float f = 0.0f;
#pragma unroll
    for (int r = 0; r < cR; r++) f += t0[r] * w02[((size_t)layer * cR + r) * cC + o];
    (ws + OFF_F0)[b * cC + o] = f / (float)cN;
  }
}

// --- inverse v6 (MFMA split-fp16, LDS-staged A with register prefetch):
//     D[c,n] = sum_{k=0..319} A[k,c]*B[k,n]; 5 super-chunks of K=64 (2 t-chunks).
//     A staged cooperatively global->regs->LDS one super-chunk ahead; B bases
//     generated into LDS (stride 36 halfs = ~2-way banks, free); conv B from regs.
__global__ void __launch_bounds__(256, 3) k_inverse(float* __restrict__ h,
                                                    const float* __restrict__ ws,
                                                    const float* __restrict__ bconv,
                                                    int layer, int do_gelu) {
  __shared__ __align__(16) _Float16 lAh[2][64 * 36];
  __shared__ __align__(16) _Float16 lAl[2][64 * 36];
  __shared__ __align__(16) _Float16 lBh[2][64 * 36];
  __shared__ __align__(16) _Float16 lBl[2][64 * 36];
  int b = blockIdx.y;
  int n_blk = blockIdx.x * 64;
  int tid = threadIdx.x;
  int lane = tid & 63, w = tid >> 6;
  int l15 = lane & 15, quad = lane >> 4;
  int p = tid >> 2, sub = tid & 3;  // basis-gen / A-stage map (p==ac, sub==aseg)
  const float4* pA = (const float4*)(ws + OFF_PACKA) + (size_t)b * cN;
  const float4* pB = (const float4*)(ws + OFF_PACKB) + (size_t)b * cN;
  const float2* pC = (const float2*)(ws + OFF_PACKC) + (size_t)b * cN;
  // anchors for basis point p
  float4 a4 = pA[n_blk + p];
  float4 b4 = pB[n_blk + p];
  float mval_p = pC[n_blk + p].y;
  cpx ex{a4.x, a4.y}, ey{a4.z, a4.w}, ex8{b4.x, b4.y}, ey4{b4.z, b4.w};
  cpx ex2 = cmul(ex, ex);
  cpx ex3 = cmul(ex2, ex);
  cpx ex4v = cmul(ex2, ex2);
  cpx ex12 = cmul(ex8, ex4v);
  cpx eyp[8];
  eyp[0] = {1.0f, 0.0f};
  eyp[1] = ey;
  eyp[2] = cmul(ey, ey);
  eyp[3] = cmul(eyp[2], ey);
  eyp[4] = ey4;
  eyp[5] = cmul(ey4, ey);
  eyp[6] = cmul(ey4, eyp[2]);
  eyp[7] = cmul(ey4, eyp[3]);
  // this lane's output column + mask
  int ncol = n_blk + w * 16 + l15;
  float mcol = pC[ncol].y;
  // conv B-frags from fp32 h, read BEFORE first barrier (in-place safe:
  // blocks are column-partitioned; stores happen only in the epilogue)
  float* hb = h + (size_t)b * cC * cN;
  f16x8 cBh[2], cBl[2];
#pragma unroll
  for (int t = 0; t < 2; t++) {
#pragma unroll
    for (int j = 0; j < 8; j++) {
      int i = t * 32 + quad * 8 + j;
      float v = hb[(size_t)i * cN + ncol];
      _Float16 hi, lo;
      split16(v, hi, lo);
      cBh[t][j] = hi;
      cBl[t][j] = lo;
    }
  }
  // A prefetch pointers: thread stages rows of channel p, k-segment sub*8
  const _Float16* FAh = (const _Float16*)(ws + OFF_FAH) + ((size_t)b * cC + p) * 320 + sub * 8;
  const _Float16* FAl = (const _Float16*)(ws + OFF_FAL) + ((size_t)b * cC + p) * 320 + sub * 8;
  f16x8 pf_h0 = *(const f16x8*)(FAh);        // sc=0, t=0
  f16x8 pf_h1 = *(const f16x8*)(FAh + 32);   // sc=0, t=1
  f16x8 pf_l0 = *(const f16x8*)(FAl);
  f16x8 pf_l1 = *(const f16x8*)(FAl + 32);
  f32x4 acc0[4], acc1[4];
  f32x4 zz = {0.0f, 0.0f, 0.0f, 0.0f};
#pragma unroll
  for (int i = 0; i < 4; i++) { acc0[i] = zz; acc1[i] = zz; }
  for (int sc = 0; sc < 5; sc++) {
    __syncthreads();  // previous super-chunk fully consumed
    // stage this super-chunk's A (from prefetch regs)
    *(f16x8*)&lAh[0][p * 36 + sub * 8] = pf_h0;
    *(f16x8*)&lAh[1][p * 36 + sub * 8] = pf_h1;
    *(f16x8*)&lAl[0][p * 36 + sub * 8] = pf_l0;
    *(f16x8*)&lAl[1][p * 36 + sub * 8] = pf_l1;
    if (sc < 4) {
      // generate B bases for kx = 4sc+sub: cos rows -> t0, sin rows -> t1
      cpx base;
      if (sc == 0) base = cpx{1.0f, 0.0f};
      else if (sc == 1) base = ex4v;
      else if (sc == 2) base = ex8;
      else base = ex12;
      cpx u;
      if (sub == 0) u = base;
      else if (sub == 1) u = cmul(base, ex);
      else if (sub == 2) u = cmul(base, ex2);
      else u = cmul(base, ex3);
      u.x *= mval_p;
      u.y *= mval_p;
      f16x8 ch, cl, sh, sl;
#pragma unroll
      for (int ky = 0; ky < 8; ky++) {
        cpx m = cmul(u, eyp[ky]);
        _Float16 hi, lo;
        split16(m.x, hi, lo);
        ch[ky] = hi; cl[ky] = lo;
        split16(m.y, hi, lo);
        sh[ky] = hi; sl[ky] = lo;
      }
      *(f16x8*)&lBh[0][p * 36 + sub * 8] = ch;
      *(f16x8*)&lBl[0][p * 36 + sub * 8] = cl;
      *(f16x8*)&lBh[1][p * 36 + sub * 8] = sh;
      *(f16x8*)&lBl[1][p * 36 + sub * 8] = sl;
    }
    __syncthreads();
    if (sc < 4) {
      // prefetch next super-chunk's A (consumed next iteration -> latency hidden)
      int koff = (sc + 1) * 64;
      pf_h0 = *(const f16x8*)(FAh + koff);
      pf_h1 = *(const f16x8*)(FAh + koff + 32);
      pf_l0 = *(const f16x8*)(FAl + koff);
      pf_l1 = *(const f16x8*)(FAl + koff + 32);
    }
#pragma unroll
    for (int t = 0; t < 2; t++) {
      f16x8 Af_h[4], Af_l[4];
#pragma unroll
      for (int mt = 0; mt < 4; mt++) {
        Af_h[mt] = *(const f16x8*)&lAh[t][(mt * 16 + l15) * 36 + quad * 8];
        Af_l[mt] = *(const f16x8*)&lAl[t][(mt * 16 + l15) * 36 + quad * 8];
      }
      f16x8 Bf_h, Bf_l;
      if (sc < 4) {
        Bf_h = *(const f16x8*)&lBh[t][(w * 16 + l15) * 36 + quad * 8];
        Bf_l = *(const f16x8*)&lBl[t][(w * 16 + l15) * 36 + quad * 8];
      } else {
        Bf_h = cBh[t];
        Bf_l = cBl[t];
      }
#pragma unroll
      for (int mt = 0; mt < 4; mt++) {
        acc0[mt] = __builtin_amdgcn_mfma_f32_16x16x32_f16(Af_h[mt], Bf_h, acc0[mt], 0, 0, 0);
        acc1[mt] = __builtin_amdgcn_mfma_f32_16x16x32_f16(Af_h[mt], Bf_l, acc1[mt], 0, 0, 0);
        acc1[mt] = __builtin_amdgcn_mfma_f32_16x16x32_f16(Af_l[mt], Bf_h, acc1[mt], 0, 0, 0);
      }
    }
  }
  // epilogue: + F0*mask + bconv, gelu, store (C/D: col=l15, row=quad*4+r)
  const float* F0B = ws + OFF_F0 + (size_t)b * cC;
  const float inv1024 = 1.0f / 1024.0f;
#pragma unroll
  for (int mt = 0; mt < 4; mt++) {
#pragma unroll
    for (int r = 0; r < 4; r++) {
      int row = mt * 16 + quad * 4 + r;
      float v = acc0[mt][r] + acc1[mt][r] * inv1024 + F0B[row] * mcol +
                bconv[layer * cC + row];
      if (do_gelu) v = gelu_f(v);
      hb[(size_t)row * cN + ncol] = v;
    }
  }
}

// --- final MLP: gelu(h^T @ fc1 + b1) @ fc2 + b2
__global__ void __launch_bounds__(256) k_final(const float* __restrict__ h,
                                               const float* __restrict__ fc1_w,
                                               const float* __restrict__ fc1_b,
                                               const float* __restrict__ fc2_w,
                                               const float* __restrict__ fc2_b,
                                               float* __restrict__ out) {
  int b = blockIdx.y;
  int n0 = blockIdx.x * 64;
  int tid = threadIdx.x;
  int tn = tid & 63;
  int tg = tid >> 6;
  __shared__ __align__(16) float w1s[cC * 128];
  __shared__ __align__(16) float hT[cC * 64];
  __shared__ float red[4 * 64];
  const float* hb = h + (size_t)b * cC * cN;
#pragma unroll
  for (int i = 0; i < 16; i++) {
    int e = tid + i * 256;
    int c = e >> 6, nnx = e & 63;
    hT[c * 64 + nnx] = hb[(size_t)c * cN + n0 + nnx];
  }
#pragma unroll
  for (int i = 0; i < 32; i++) {
    int e = tid + i * 256;
    w1s[e] = fc1_w[e];
  }
  __syncthreads();
  int j0 = tg * 32;
  float acc[32] = {};
  for (int c = 0; c < cC; c++) {
    float hv = hT[c * 64 + tn];
#pragma unroll
    for (int jj = 0; jj < 32; jj += 4) {
      float4 w4 = *(const float4*)&w1s[c * 128 + j0 + jj];
      acc[jj] += hv * w4.x;
      acc[jj + 1] += hv * w4.y;
      acc[jj + 2] += hv * w4.z;
      acc[jj + 3] += hv * w4.w;
    }
  }
  float s = 0.0f;
#pragma unroll
  for (int jj = 0; jj < 32; jj++) {
    int j = j0 + jj;
    float v = gelu_f(acc[jj] + fc1_b[j]);
    s += v * fc2_w[j];
  }
  red[tg * 64 + tn] = s;
  __syncthreads();
  if (tg == 0) {
    float r = red[tn] + red[64 + tn] + red[128 + tn] + red[192 + tn] + fc2_b[0];
    out[(size_t)b * cN + n0 + tn] = r;
  }
}

extern "C" void kernel_launch(void* const* d_in, const int* in_sizes, int n_in,
                              void* d_out, int out_size, void* d_ws, size_t ws_size,
                              hipStream_t stream) {
  const float* x = (const float*)d_in[0];
  const float* fc0_w = (const float*)d_in[1];
  const float* fc0_b = (const float*)d_in[2];
  const float* wc1 = (const float*)d_in[3];
  const float* wc2 = (const float*)d_in[4];
  const float* ws1 = (const float*)d_in[5];
  const float* ws2 = (const float*)d_in[6];
  const float* w01 = (const float*)d_in[7];
  const float* w02 = (const float*)d_in[8];
  const float* wconv = (const float*)d_in[9];
  const float* bconv = (const float*)d_in[10];
  const float* fc1_w = (const float*)d_in[11];
  const float* fc1_b = (const float*)d_in[12];
  const float* fc2_w = (const float*)d_in[13];
  const float* fc2_b = (const float*)d_in[14];
  float* ws = (float*)d_ws;
  float* out = (float*)d_out;
  float* h = ws + OFF_H;

  hipLaunchKernelGGL(k_prep, dim3(cB * cN / 256), dim3(256), 0, stream, x, fc0_w, fc0_b, ws);
  for (int l = 0; l < cNL; l++) {
    hipLaunchKernelGGL(k_forward, dim3(32, cB), dim3(256), 0, stream, h, ws,
                       ws + OFF_PC, ws + OFF_PS);
    hipLaunchKernelGGL(k_reduce, dim3(512), dim3(256), 0, stream,
                       ws + OFF_PC, ws + OFF_PS, ws + OFF_XC, ws + OFF_XS);
    hipLaunchKernelGGL(k_lowrank, dim3(cB, cK), dim3(64), 0, stream, ws + OFF_XC,
                       ws + OFF_XS, wc1, wc2, ws1, ws2, w01, w02, wconv, ws, l);
    hipLaunchKernelGGL(k_inverse, dim3(cN / 64, cB), dim3(256), 0, stream, h, ws,
                       bconv, l, (l != cNL - 1) ? 1 : 0);
  }
  hipLaunchKernelGGL(k_final, dim3(cN / 64, cB), dim3(256), 0, stream, h, fc1_w,
                     fc1_b, fc2_w, fc2_b, out);
}

// Round 12
// 474.189 us; speedup vs baseline: 1.5128x; 1.0262x over previous
//
#include <hip/hip_runtime.h>
#include <math.h>

namespace {
constexpr int cB = 16, cN = 8192, cC = 64, cK = 128, cR = 4, cNL = 4;
constexpr float kTwoPi = 6.28318530717958647692f;

// workspace layout (float offsets)
constexpr size_t OFF_H     = 0;                                // 8,388,608
constexpr size_t OFF_PACKA = (size_t)cB * cC * cN;             // +524,288
constexpr size_t OFF_PACKB = OFF_PACKA + (size_t)cB * cN * 4;  // +524,288
constexpr size_t OFF_PACKC = OFF_PACKB + (size_t)cB * cN * 4;  // +262,144
constexpr size_t OFF_PC    = OFF_PACKC + (size_t)cB * cN * 2;  // 512 slots * 8192
constexpr size_t OFF_PS    = OFF_PC + (size_t)512 * 8192;
constexpr size_t OFF_XC    = OFF_PS + (size_t)512 * 8192;
constexpr size_t OFF_XS    = OFF_XC + (size_t)cB * cC * cK;
constexpr size_t OFF_FAH   = OFF_XS + (size_t)cB * cC * cK;    // 163,840 floats
constexpr size_t OFF_FAL   = OFF_FAH + (size_t)cB * cC * 320 / 2;
constexpr size_t OFF_F0    = OFF_FAL + (size_t)cB * cC * 320 / 2;
constexpr size_t OFF_FW    = OFF_F0 + (size_t)cB * cC;         // fc1_w split: 8192+8192 halfs
// end = OFF_FW + 8192 = 18,686,976 floats = 74.75 MB

typedef _Float16 f16x8 __attribute__((ext_vector_type(8)));
typedef _Float16 f16x4 __attribute__((ext_vector_type(4)));
typedef float f32x4 __attribute__((ext_vector_type(4)));

__device__ __forceinline__ float gelu_f(float x) {
  return 0.5f * x * (1.0f + erff(x * 0.7071067811865475244f));
}

struct cpx { float x, y; };
__device__ __forceinline__ cpx cmul(cpx a, cpx b) {
  cpx r;
  r.x = fmaf(a.x, b.x, -(a.y * b.y));
  r.y = fmaf(a.x, b.y, a.y * b.x);
  return r;
}

__device__ __forceinline__ void split16(float v, _Float16& hi, _Float16& lo) {
  hi = (_Float16)v;
  lo = (_Float16)((v - (float)hi) * 1024.0f);
}
}  // namespace

// --- prep: fc0 into (B,C,N), per-point phase factors
__global__ void __launch_bounds__(256) k_prep(const float* __restrict__ x,
                                              const float* __restrict__ fc0_w,
                                              const float* __restrict__ fc0_b,
                                              float* __restrict__ ws) {
  int t = blockIdx.x * 256 + threadIdx.x;
  int b = t >> 13;
  int n = t & (cN - 1);
  const float* xp = x + (size_t)t * 7;
  float f0 = xp[0], f1 = xp[1], f2 = xp[2];
  float gx = xp[3], gy = xp[4], w = xp[5], m = xp[6];
  float ax = kTwoPi * gx, ay = kTwoPi * gy;
  float sx, cx, sy, cy, s8x, c8x, s4y, c4y;
  sincosf(ax, &sx, &cx);
  sincosf(ay, &sy, &cy);
  sincosf(8.0f * ax, &s8x, &c8x);
  sincosf(4.0f * ay, &s4y, &c4y);
  ((float4*)(ws + OFF_PACKA))[t] = make_float4(cx, sx, cy, sy);
  ((float4*)(ws + OFF_PACKB))[t] = make_float4(c8x, s8x, c4y, s4y);
  ((float2*)(ws + OFF_PACKC))[t] = make_float2(w * (float)cN * m, m);
  float* h = ws + OFF_H + (size_t)b * cC * cN + n;
#pragma unroll
  for (int c = 0; c < cC; c++) {
    float v = fc0_b[c] + f0 * fc0_w[c] + f1 * fc0_w[cC + c] + f2 * fc0_w[2 * cC + c];
    h[(size_t)c * cN] = v;
  }
}

// --- prepw: split fc1_w into [j=128][c=64] hi/lo halfs (runs once)
__global__ void k_prepw(const float* __restrict__ fc1_w, float* __restrict__ ws) {
  int j = threadIdx.x;  // 0..127
  _Float16* FWh = (_Float16*)(ws + OFF_FW);
  _Float16* FWl = FWh + 128 * 64;
  for (int c = 0; c < cC; c++) {
    _Float16 hi, lo;
    split16(fc1_w[c * 128 + j], hi, lo);
    FWh[j * 64 + c] = hi;
    FWl[j * 64 + c] = lo;
  }
}

// --- forward (MFMA split-fp16): per-block partial Xc/Xs, 512 blocks.
__global__ void __launch_bounds__(256, 2) k_forward(const float* __restrict__ hg,
                                                    const float* __restrict__ ws,
                                                    float* __restrict__ Pc,
                                                    float* __restrict__ Ps) {
  __shared__ __align__(16) _Float16 lAh[64 * 40];
  __shared__ __align__(16) _Float16 lAl[64 * 40];
  __shared__ __align__(16) _Float16 lWh[256 * 40];
  __shared__ __align__(16) _Float16 lWl[256 * 40];
  int b = blockIdx.y, nb = blockIdx.x;  // nb 0..31
  int n_base = nb * 256;
  int tid = threadIdx.x;
  int lane = tid & 63, w = tid >> 6;
  int l15 = lane & 15, quad = lane >> 4;
  int sc = tid & 63, skg = tid >> 6;   // H: channel, 8-pt group
  int mg = tid >> 3, pg = tid & 7;     // W: 4-mode group, 4-pt group
  int kx = mg >> 1, ky0 = (mg & 1) * 4;
  const float4* pA = (const float4*)(ws + OFF_PACKA) + (size_t)b * cN;
  const float4* pB = (const float4*)(ws + OFF_PACKB) + (size_t)b * cN;
  const float2* pC = (const float2*)(ws + OFF_PACKC) + (size_t)b * cN;
  const float* hb = hg + (size_t)b * cC * cN;
  f32x4 acc0[4][4], acc1[4][4];
  f32x4 zz = {0.0f, 0.0f, 0.0f, 0.0f};
#pragma unroll
  for (int i = 0; i < 4; i++)
#pragma unroll
    for (int j = 0; j < 4; j++) { acc0[i][j] = zz; acc1[i][j] = zz; }

  for (int s = 0; s < 8; s++) {
    int n0 = n_base + s * 32;
    {
      const float* hrow = hb + (size_t)sc * cN + n0 + skg * 8;
      float4 va = *(const float4*)hrow;
      float4 vb = *(const float4*)(hrow + 4);
      float vals[8] = {va.x, va.y, va.z, va.w, vb.x, vb.y, vb.z, vb.w};
      f16x8 hi8, lo8;
#pragma unroll
      for (int e = 0; e < 8; e++) {
        _Float16 hv, lv;
        split16(vals[e], hv, lv);
        hi8[e] = hv;
        lo8[e] = lv;
      }
      *(f16x8*)&lAh[sc * 40 + skg * 8] = hi8;
      *(f16x8*)&lAl[sc * 40 + skg * 8] = lo8;
    }
    {
      _Float16 chi[4][4], clo[4][4], shi[4][4], slo[4][4];  // [j][q]
#pragma unroll
      for (int q = 0; q < 4; q++) {
        int p = n0 + pg * 4 + q;
        float4 a4 = pA[p];
        float4 b4 = pB[p];
        float wsz = pC[p].x;
        cpx ex{a4.x, a4.y}, ey{a4.z, a4.w}, ex8{b4.x, b4.y}, ey4{b4.z, b4.w};
        cpx ex2 = cmul(ex, ex);
        cpx ex4v = cmul(ex2, ex2);
        cpx u{wsz, 0.0f};
        if (kx & 1) u = cmul(u, ex);
        if (kx & 2) u = cmul(u, ex2);
        if (kx & 4) u = cmul(u, ex4v);
        if (kx & 8) u = cmul(u, ex8);
        cpx v;
        if (ky0) v = ey4; else v = cpx{1.0f, 0.0f};
#pragma unroll
        for (int j = 0; j < 4; j++) {
          cpx m = cmul(u, v);
          split16(m.x, chi[j][q], clo[j][q]);
          split16(m.y, shi[j][q], slo[j][q]);
          v = cmul(v, ey);
        }
      }
      int mbase = kx * 8 + ky0;
#pragma unroll
      for (int j = 0; j < 4; j++) {
        int mc = mbase + j, ms = 128 + mbase + j;
        f16x4 t0 = {chi[j][0], chi[j][1], chi[j][2], chi[j][3]};
        f16x4 t1 = {clo[j][0], clo[j][1], clo[j][2], clo[j][3]};
        f16x4 t2 = {shi[j][0], shi[j][1], shi[j][2], shi[j][3]};
        f16x4 t3 = {slo[j][0], slo[j][1], slo[j][2], slo[j][3]};
        *(f16x4*)&lWh[mc * 40 + pg * 4] = t0;
        *(f16x4*)&lWl[mc * 40 + pg * 4] = t1;
        *(f16x4*)&lWh[ms * 40 + pg * 4] = t2;
        *(f16x4*)&lWl[ms * 40 + pg * 4] = t3;
      }
    }
    __syncthreads();
    f16x8 Ahf[4], Alf[4];
#pragma unroll
    for (int mt = 0; mt < 4; mt++) {
      Ahf[mt] = *(const f16x8*)&lAh[(mt * 16 + l15) * 40 + quad * 8];
      Alf[mt] = *(const f16x8*)&lAl[(mt * 16 + l15) * 40 + quad * 8];
    }
#pragma unroll
    for (int nt = 0; nt < 4; nt++) {
      int row = w * 64 + nt * 16 + l15;
      f16x8 Bh = *(const f16x8*)&lWh[row * 40 + quad * 8];
      f16x8 Bl = *(const f16x8*)&lWl[row * 40 + quad * 8];
#pragma unroll
      for (int mt = 0; mt < 4; mt++) {
        acc0[mt][nt] = __builtin_amdgcn_mfma_f32_16x16x32_f16(Ahf[mt], Bh, acc0[mt][nt], 0, 0, 0);
        acc1[mt][nt] = __builtin_amdgcn_mfma_f32_16x16x32_f16(Ahf[mt], Bl, acc1[mt][nt], 0, 0, 0);
        acc1[mt][nt] = __builtin_amdgcn_mfma_f32_16x16x32_f16(Alf[mt], Bh, acc1[mt][nt], 0, 0, 0);
      }
    }
    __syncthreads();
  }
  float* pcb = Pc + (size_t)(b * 32 + nb) * 8192;
  float* psb = Ps + (size_t)(b * 32 + nb) * 8192;
  const float inv1024 = 1.0f / 1024.0f;
#pragma unroll
  for (int mt = 0; mt < 4; mt++)
#pragma unroll
    for (int nt = 0; nt < 4; nt++) {
      int nn = w * 64 + nt * 16 + l15;
      float* dst = (nn < 128) ? pcb : psb;
      int col = nn & 127;
#pragma unroll
      for (int r = 0; r < 4; r++) {
        int c = mt * 16 + quad * 4 + r;
        dst[c * 128 + col] = acc0[mt][nt][r] + acc1[mt][nt][r] * inv1024;
      }
    }
}

// --- reduce 32 partials -> Xc/Xs
__global__ void __launch_bounds__(256) k_reduce(const float* __restrict__ Pc,
                                                const float* __restrict__ Ps,
                                                float* __restrict__ Xc,
                                                float* __restrict__ Xs) {
  int idx = blockIdx.x * 256 + threadIdx.x;  // 0..131071
  int b = idx >> 13;
  int rest = idx & 8191;
  float sc = 0.0f, ss = 0.0f;
#pragma unroll
  for (int nb = 0; nb < 32; nb++) {
    sc += Pc[(size_t)(b * 32 + nb) * 8192 + rest];
    ss += Ps[(size_t)(b * 32 + nb) * 8192 + rest];
  }
  Xc[idx] = sc;
  Xs[idx] = ss;
}

// --- low-rank mixing; one wave per (b,k); writes split-fp16 A-matrix for k_inverse
__global__ void __launch_bounds__(64) k_lowrank(const float* __restrict__ Xc,
                                                const float* __restrict__ Xs,
                                                const float* __restrict__ wc1,
                                                const float* __restrict__ wc2,
                                                const float* __restrict__ ws1,
                                                const float* __restrict__ ws2,
                                                const float* __restrict__ w01,
                                                const float* __restrict__ w02,
                                                const float* __restrict__ wconv,
                                                float* __restrict__ ws, int layer) {
  int b = blockIdx.x;
  int k = blockIdx.y;
  int tid = threadIdx.x;
  const float* xcb = Xc + (size_t)b * cC * cK;
  const float* xsb = Xs + (size_t)b * cC * cK;
  float xcv = xcb[(size_t)tid * cK + k];
  float xsv = -xsb[(size_t)tid * cK + k];
  const float* c1 = wc1 + (size_t)layer * cC * cR * cK + (size_t)tid * cR * cK + k;
  const float* s1 = ws1 + (size_t)layer * cC * cR * cK + (size_t)tid * cR * cK + k;
  float A1[cR], A2[cR], B1[cR], B2[cR];
#pragma unroll
  for (int r = 0; r < cR; r++) {
    float w1c = c1[(size_t)r * cK];
    float w1sv = s1[(size_t)r * cK];
    A1[r] = xcv * w1c;
    A2[r] = xcv * w1sv;
    B1[r] = xsv * w1c;
    B2[r] = xsv * w1sv;
  }
#pragma unroll
  for (int r = 0; r < cR; r++) {
#pragma unroll
    for (int off = 32; off > 0; off >>= 1) {
      A1[r] += __shfl_xor(A1[r], off);
      A2[r] += __shfl_xor(A2[r], off);
      B1[r] += __shfl_xor(B1[r], off);
      B2[r] += __shfl_xor(B2[r], off);
    }
  }
  const float scale = 2.0f / (float)cN;
  const float* c2 = wc2 + (size_t)layer * cR * cC * cK;
  const float* s2 = ws2 + (size_t)layer * cR * cC * cK;
  int o = tid;
  float fc = 0.0f, fs = 0.0f;
#pragma unroll
  for (int r = 0; r < cR; r++) {
    float w2c = c2[((size_t)r * cC + o) * cK + k];
    float w2s = s2[((size_t)r * cC + o) * cK + k];
    fc += A1[r] * w2c - B2[r] * w2s;
    fs += B1[r] * w2c + A2[r] * w2s;
  }
  _Float16* FAh = (_Float16*)(ws + OFF_FAH);
  _Float16* FAl = (_Float16*)(ws + OFF_FAL);
  size_t abase = ((size_t)b * cC + o) * 320;
  int rowc = ((k >> 5) << 6) + (k & 31);
  float vc = scale * fc;
  float vs = -scale * fs;
  _Float16 hi, lo;
  split16(vc, hi, lo);
  FAh[abase + rowc] = hi;
  FAl[abase + rowc] = lo;
  split16(vs, hi, lo);
  FAh[abase + rowc + 32] = hi;
  FAl[abase + rowc + 32] = lo;
  if (k < 64) {
    float wv = wconv[(size_t)layer * 4096 + (size_t)k * cC + o];
    split16(wv, hi, lo);
    FAh[abase + 256 + k] = hi;
    FAl[abase + 256 + k] = lo;
  }
  if (k == 0) {
    float t0[cR];
#pragma unroll
    for (int r = 0; r < cR; r++)
      t0[r] = xcv * w01[((size_t)layer * cC + tid) * cR + r];
#pragma unroll
    for (int r = 0; r < cR; r++) {
#pragma unroll
      for (int off = 32; off > 0; off >>= 1) t0[r] += __shfl_xor(t0[r], off);
    }
    float f = 0.0f;
#pragma unroll
    for (int r = 0; r < cR; r++) f += t0[r] * w02[((size_t)layer * cR + r) * cC + o];
    (ws + OFF_F0)[b * cC + o] = f / (float)cN;
  }
}

// --- inverse v6 (MFMA split-fp16, LDS-staged A with register prefetch)
__global__ void __launch_bounds__(256, 3) k_inverse(float* __restrict__ h,
                                                    const float* __restrict__ ws,
                                                    const float* __restrict__ bconv,
                                                    int layer, int do_gelu) {
  __shared__ __align__(16) _Float16 lAh[2][64 * 36];
  __shared__ __align__(16) _Float16 lAl[2][64 * 36];
  __shared__ __align__(16) _Float16 lBh[2][64 * 36];
  __shared__ __align__(16) _Float16 lBl[2][64 * 36];
  int b = blockIdx.y;
  int n_blk = blockIdx.x * 64;
  int tid = threadIdx.x;
  int lane = tid & 63, w = tid >> 6;
  int l15 = lane & 15, quad = lane >> 4;
  int p = tid >> 2, sub = tid & 3;
  const float4* pA = (const float4*)(ws + OFF_PACKA) + (size_t)b * cN;
  const float4* pB = (const float4*)(ws + OFF_PACKB) + (size_t)b * cN;
  const float2* pC = (const float2*)(ws + OFF_PACKC) + (size_t)b * cN;
  float4 a4 = pA[n_blk + p];
  float4 b4 = pB[n_blk + p];
  float mval_p = pC[n_blk + p].y;
  cpx ex{a4.x, a4.y}, ey{a4.z, a4.w}, ex8{b4.x, b4.y}, ey4{b4.z, b4.w};
  cpx ex2 = cmul(ex, ex);
  cpx ex3 = cmul(ex2, ex);
  cpx ex4v = cmul(ex2, ex2);
  cpx ex12 = cmul(ex8, ex4v);
  cpx eyp[8];
  eyp[0] = {1.0f, 0.0f};
  eyp[1] = ey;
  eyp[2] = cmul(ey, ey);
  eyp[3] = cmul(eyp[2], ey);
  eyp[4] = ey4;
  eyp[5] = cmul(ey4, ey);
  eyp[6] = cmul(ey4, eyp[2]);
  eyp[7] = cmul(ey4, eyp[3]);
  int ncol = n_blk + w * 16 + l15;
  float mcol = pC[ncol].y;
  float* hb = h + (size_t)b * cC * cN;
  f16x8 cBh[2], cBl[2];
#pragma unroll
  for (int t = 0; t < 2; t++) {
#pragma unroll
    for (int j = 0; j < 8; j++) {
      int i = t * 32 + quad * 8 + j;
      float v = hb[(size_t)i * cN + ncol];
      _Float16 hi, lo;
      split16(v, hi, lo);
      cBh[t][j] = hi;
      cBl[t][j] = lo;
    }
  }
  const _Float16* FAh = (const _Float16*)(ws + OFF_FAH) + ((size_t)b * cC + p) * 320 + sub * 8;
  const _Float16* FAl = (const _Float16*)(ws + OFF_FAL) + ((size_t)b * cC + p) * 320 + sub * 8;
  f16x8 pf_h0 = *(const f16x8*)(FAh);
  f16x8 pf_h1 = *(const f16x8*)(FAh + 32);
  f16x8 pf_l0 = *(const f16x8*)(FAl);
  f16x8 pf_l1 = *(const f16x8*)(FAl + 32);
  f32x4 acc0[4], acc1[4];
  f32x4 zz = {0.0f, 0.0f, 0.0f, 0.0f};
#pragma unroll
  for (int i = 0; i < 4; i++) { acc0[i] = zz; acc1[i] = zz; }
  for (int sc = 0; sc < 5; sc++) {
    __syncthreads();
    *(f16x8*)&lAh[0][p * 36 + sub * 8] = pf_h0;
    *(f16x8*)&lAh[1][p * 36 + sub * 8] = pf_h1;
    *(f16x8*)&lAl[0][p * 36 + sub * 8] = pf_l0;
    *(f16x8*)&lAl[1][p * 36 + sub * 8] = pf_l1;
    if (sc < 4) {
      cpx base;
      if (sc == 0) base = cpx{1.0f, 0.0f};
      else if (sc == 1) base = ex4v;
      else if (sc == 2) base = ex8;
      else base = ex12;
      cpx u;
      if (sub == 0) u = base;
      else if (sub == 1) u = cmul(base, ex);
      else if (sub == 2) u = cmul(base, ex2);
      else u = cmul(base, ex3);
      u.x *= mval_p;
      u.y *= mval_p;
      f16x8 ch, cl, sh, sl;
#pragma unroll
      for (int ky = 0; ky < 8; ky++) {
        cpx m = cmul(u, eyp[ky]);
        _Float16 hi, lo;
        split16(m.x, hi, lo);
        ch[ky] = hi; cl[ky] = lo;
        split16(m.y, hi, lo);
        sh[ky] = hi; sl[ky] = lo;
      }
      *(f16x8*)&lBh[0][p * 36 + sub * 8] = ch;
      *(f16x8*)&lBl[0][p * 36 + sub * 8] = cl;
      *(f16x8*)&lBh[1][p * 36 + sub * 8] = sh;
      *(f16x8*)&lBl[1][p * 36 + sub * 8] = sl;
    }
    __syncthreads();
    if (sc < 4) {
      int koff = (sc + 1) * 64;
      pf_h0 = *(const f16x8*)(FAh + koff);
      pf_h1 = *(const f16x8*)(FAh + koff + 32);
      pf_l0 = *(const f16x8*)(FAl + koff);
      pf_l1 = *(const f16x8*)(FAl + koff + 32);
    }
#pragma unroll
    for (int t = 0; t < 2; t++) {
      f16x8 Af_h[4], Af_l[4];
#pragma unroll
      for (int mt = 0; mt < 4; mt++) {
        Af_h[mt] = *(const f16x8*)&lAh[t][(mt * 16 + l15) * 36 + quad * 8];
        Af_l[mt] = *(const f16x8*)&lAl[t][(mt * 16 + l15) * 36 + quad * 8];
      }
      f16x8 Bf_h, Bf_l;
      if (sc < 4) {
        Bf_h = *(const f16x8*)&lBh[t][(w * 16 + l15) * 36 + quad * 8];
        Bf_l = *(const f16x8*)&lBl[t][(w * 16 + l15) * 36 + quad * 8];
      } else {
        Bf_h = cBh[t];
        Bf_l = cBl[t];
      }
#pragma unroll
      for (int mt = 0; mt < 4; mt++) {
        acc0[mt] = __builtin_amdgcn_mfma_f32_16x16x32_f16(Af_h[mt], Bf_h, acc0[mt], 0, 0, 0);
        acc1[mt] = __builtin_amdgcn_mfma_f32_16x16x32_f16(Af_h[mt], Bf_l, acc1[mt], 0, 0, 0);
        acc1[mt] = __builtin_amdgcn_mfma_f32_16x16x32_f16(Af_l[mt], Bf_h, acc1[mt], 0, 0, 0);
      }
    }
  }
  const float* F0B = ws + OFF_F0 + (size_t)b * cC;
  const float inv1024 = 1.0f / 1024.0f;
#pragma unroll
  for (int mt = 0; mt < 4; mt++) {
#pragma unroll
    for (int r = 0; r < 4; r++) {
      int row = mt * 16 + quad * 4 + r;
      float v = acc0[mt][r] + acc1[mt][r] * inv1024 + F0B[row] * mcol +
                bconv[layer * cC + row];
      if (do_gelu) v = gelu_f(v);
      hb[(size_t)row * cN + ncol] = v;
    }
  }
}

// --- final MLP v2 (MFMA split-fp16): D[j=128, n=64] = sum_c fc1_w[c,j]*h[c,n];
//     epilogue: gelu(D + b1) dot fc2_w reduced across quads.
__global__ void __launch_bounds__(256, 2) k_final(const float* __restrict__ h,
                                                  const float* __restrict__ ws,
                                                  const float* __restrict__ fc1_b,
                                                  const float* __restrict__ fc2_w,
                                                  const float* __restrict__ fc2_b,
                                                  float* __restrict__ out) {
  __shared__ __align__(16) _Float16 lFh[128 * 68];  // stride 68: 2-way banks, free
  __shared__ __align__(16) _Float16 lFl[128 * 68];
  int b = blockIdx.y;
  int n_blk = blockIdx.x * 64;
  int tid = threadIdx.x;
  int lane = tid & 63, w = tid >> 6;
  int l15 = lane & 15, quad = lane >> 4;
  // stage FW (split fc1_w [j][64]) into LDS
  {
    const _Float16* FWh = (const _Float16*)(ws + OFF_FW);
    const _Float16* FWl = FWh + 128 * 64;
    int row = tid & 127, which = tid >> 7;
    const _Float16* src = (which ? FWl : FWh) + row * 64;
    _Float16* dst = (which ? lFl : lFh) + row * 68;
#pragma unroll
    for (int i = 0; i < 8; i++)
      *(f16x8*)&dst[i * 8] = *(const f16x8*)&src[i * 8];
  }
  // B-frags: h[c][ncol] split
  int ncol = n_blk + w * 16 + l15;
  const float* hb = h + (size_t)b * cC * cN;
  f16x8 hBh[2], hBl[2];
#pragma unroll
  for (int t = 0; t < 2; t++) {
#pragma unroll
    for (int j = 0; j < 8; j++) {
      int c = t * 32 + quad * 8 + j;
      float v = hb[(size_t)c * cN + ncol];
      _Float16 hi, lo;
      split16(v, hi, lo);
      hBh[t][j] = hi;
      hBl[t][j] = lo;
    }
  }
  __syncthreads();
  f32x4 acc0[8], acc1[8];
  f32x4 zz = {0.0f, 0.0f, 0.0f, 0.0f};
#pragma unroll
  for (int i = 0; i < 8; i++) { acc0[i] = zz; acc1[i] = zz; }
#pragma unroll
  for (int t = 0; t < 2; t++) {
#pragma unroll
    for (int mt = 0; mt < 8; mt++) {
      f16x8 Ah = *(const f16x8*)&lFh[(mt * 16 + l15) * 68 + t * 32 + quad * 8];
      f16x8 Al = *(const f16x8*)&lFl[(mt * 16 + l15) * 68 + t * 32 + quad * 8];
      acc0[mt] = __builtin_amdgcn_mfma_f32_16x16x32_f16(Ah, hBh[t], acc0[mt], 0, 0, 0);
      acc1[mt] = __builtin_amdgcn_mfma_f32_16x16x32_f16(Ah, hBl[t], acc1[mt], 0, 0, 0);
      acc1[mt] = __builtin_amdgcn_mfma_f32_16x16x32_f16(Al, hBh[t], acc1[mt], 0, 0, 0);
    }
  }
  // epilogue: gelu + dot with fc2_w over this lane's 32 j's, then quad-reduce
  const float inv1024 = 1.0f / 1024.0f;
  float s = 0.0f;
#pragma unroll
  for (int mt = 0; mt < 8; mt++) {
#pragma unroll
    for (int r = 0; r < 4; r++) {
      int j = mt * 16 + quad * 4 + r;
      float t1 = acc0[mt][r] + acc1[mt][r] * inv1024 + fc1_b[j];
      s += gelu_f(t1) * fc2_w[j];
    }
  }
  s += __shfl_xor(s, 16);
  s += __shfl_xor(s, 32);
  if (quad == 0) out[(size_t)b * cN + ncol] = s + fc2_b[0];
}

extern "C" void kernel_launch(void* const* d_in, const int* in_sizes, int n_in,
                              void* d_out, int out_size, void* d_ws, size_t ws_size,
                              hipStream_t stream) {
  const float* x = (const float*)d_in[0];
  const float* fc0_w = (const float*)d_in[1];
  const float* fc0_b = (const float*)d_in[2];
  const float* wc1 = (const float*)d_in[3];
  const float* wc2 = (const float*)d_in[4];
  const float* ws1 = (const float*)d_in[5];
  const float* ws2 = (const float*)d_in[6];
  const float* w01 = (const float*)d_in[7];
  const float* w02 = (const float*)d_in[8];
  const float* wconv = (const float*)d_in[9];
  const float* bconv = (const float*)d_in[10];
  const float* fc1_w = (const float*)d_in[11];
  const float* fc1_b = (const float*)d_in[12];
  const float* fc2_w = (const float*)d_in[13];
  const float* fc2_b = (const float*)d_in[14];
  float* ws = (float*)d_ws;
  float* out = (float*)d_out;
  float* h = ws + OFF_H;

  hipLaunchKernelGGL(k_prep, dim3(cB * cN / 256), dim3(256), 0, stream, x, fc0_w, fc0_b, ws);
  hipLaunchKernelGGL(k_prepw, dim3(1), dim3(128), 0, stream, fc1_w, ws);
  for (int l = 0; l < cNL; l++) {
    hipLaunchKernelGGL(k_forward, dim3(32, cB), dim3(256), 0, stream, h, ws,
                       ws + OFF_PC, ws + OFF_PS);
    hipLaunchKernelGGL(k_reduce, dim3(512), dim3(256), 0, stream,
                       ws + OFF_PC, ws + OFF_PS, ws + OFF_XC, ws + OFF_XS);
    hipLaunchKernelGGL(k_lowrank, dim3(cB, cK), dim3(64), 0, stream, ws + OFF_XC,
                       ws + OFF_XS, wc1, wc2, ws1, ws2, w01, w02, wconv, ws, l);
    hipLaunchKernelGGL(k_inverse, dim3(cN / 64, cB), dim3(256), 0, stream, h, ws,
                       bconv, l, (l != cNL - 1) ? 1 : 0);
  }
  hipLaunchKernelGGL(k_final, dim3(cN / 64, cB), dim3(256), 0, stream, h, ws,
                     fc1_b, fc2_w, fc2_b, out);
}